// Round 1
// 531.654 us; speedup vs baseline: 1.0135x; 1.0135x over previous
//
#include <hip/hip_runtime.h>
#include <math.h>

// Problem constants
#define FD   256
#define NH   4
#define SP3  8
#define NP   32          // SP3*NH aux points per query
#define EDIM 64          // FD/NH
#define H    128
#define NS   1024
#define BS   4
#define QTF  4           // queries per featk block (512 blocks -> 2/CU)
#define QTE  4           // queries per epik block  (512 blocks -> 2/CU)

#define TEX         (H*H)              // 16384 texels per (plane,b)
#define BATCH_ELEMS (TEX*FD)           // 4,194,304 floats
#define PAIR_B      2                  // batches processed per pass
#define PAIR_Q      (PAIR_B*NS)        // 2048 queries per pass
#define PPLANE      (PAIR_B*BATCH_ELEMS) // per-plane elems in pair buffer

// ---- workspace layout (float offsets). Total ~114.05 MB.
// ws_size proven >= 114 MB (rounds 3/5 passed); 228 MB overflowed (round 2).
#define WS_PLANES 0
#define WS_FEAT   (3*PPLANE)                       // [2048][256]
#define WS_QK     (WS_FEAT + PAIR_Q*FD)            // [2048][256]
#define WS_AUX    (WS_QK   + PAIR_Q*FD)            // [2048][96]
#define WS_WF     (WS_AUX  + PAIR_Q*NP*3)          // [2048][4][256]
#define WS_PERM   (WS_WF   + PAIR_Q*NH*FD)         // [2 pairs][2048] uint

// bf16 helpers (round-to-nearest-even). Used ONLY on the wf path (af after
// the fp32 sim dot) — sim-path quantization is amplified ~176x and is fatal.
__device__ __forceinline__ unsigned short f2bf(float f) {
  unsigned b = __float_as_uint(f);
  return (unsigned short)((b + 0x7FFFu + ((b >> 16) & 1u)) >> 16);
}
__device__ __forceinline__ float bf2f(unsigned short u) {
  return __uint_as_float(((unsigned)u) << 16);
}

// ---------------------------------------------------------------------------
// K1: transpose planes [B,C,H,W] -> [b-pair][H*W,C] (channel-last).
// 32-texel x 256-channel tiles; LDS 33 KB -> 4 blocks/CU.
// ---------------------------------------------------------------------------
__global__ __launch_bounds__(256) void tpk2(
    const float* __restrict__ xz, const float* __restrict__ xy,
    const float* __restrict__ yz, float* __restrict__ dstAll, int b0)
{
  int bid = blockIdx.x;
  int tT = bid & 511; bid >>= 9;     // 512 texel-tiles of 32
  int bl = bid & 1;   bid >>= 1;     // local batch in pair
  int pl = bid;                      // plane
  const float* src = pl == 0 ? xz : (pl == 1 ? xy : yz);
  float* dst = dstAll + (size_t)pl * PPLANE + (size_t)bl * BATCH_ELEMS;
  int b = b0 + bl;

  __shared__ float T[32 * 260];      // T[texel][channel], stride 260
  int lane = threadIdx.x & 63, w = threadIdx.x >> 6;
  int tex4 = (lane & 7) * 4;         // 0,4,..,28
  int csub = lane >> 3;              // 0..7

  const float* sbase = src + (size_t)b * FD * TEX + tT * 32;
  #pragma unroll
  for (int i = 0; i < 8; i++) {
    int c = i * 32 + w * 8 + csub;   // covers 0..255
    float4 v = *(const float4*)(sbase + (size_t)c * TEX + tex4);
    T[(tex4 + 0) * 260 + c] = v.x;
    T[(tex4 + 1) * 260 + c] = v.y;
    T[(tex4 + 2) * 260 + c] = v.z;
    T[(tex4 + 3) * 260 + c] = v.w;
  }
  __syncthreads();
  #pragma unroll
  for (int i = 0; i < 8; i++) {
    int t = w * 8 + i;
    float4 v = *(const float4*)(&T[t * 260 + lane * 4]);
    *(float4*)(dst + (size_t)(tT * 32 + t) * FD + lane * 4) = v;  // 1KB/wave
  }
}

// ---------------------------------------------------------------------------
// K1b: counting-sort the pair's 2048 queries into 256 buckets =
// (batch<<7)|top-7-Morton-bits. Any permutation is correctness-neutral;
// bucket granularity (~8 queries/cell) is all the locality we measured to
// matter. One block per pair, O(n), ~3 barriers.
// ---------------------------------------------------------------------------
__device__ __forceinline__ unsigned mort7(unsigned v) {   // 7 bits -> every 3rd
  unsigned r = 0;
  #pragma unroll
  for (int i = 0; i < 7; i++) r |= ((v >> i) & 1u) << (3 * i);
  return r;
}

__global__ __launch_bounds__(1024) void sortk(
    const float* __restrict__ qpos, unsigned* __restrict__ perm)
{
  const int pair = blockIdx.x;
  const int b0 = pair * PAIR_B;
  const int t = threadIdx.x;
  __shared__ unsigned cnt[256];
  __shared__ unsigned base[256];
  if (t < 256) cnt[t] = 0;
  __syncthreads();
  unsigned myb[2];
  #pragma unroll
  for (int r = 0; r < 2; r++) {
    int i = t + r * 1024;
    size_t qg = (size_t)b0 * NS + i;
    float x = fminf(fmaxf(qpos[qg * 3 + 0], 0.f), 1.f);
    float y = fminf(fmaxf(qpos[qg * 3 + 1], 0.f), 1.f);
    float z = fminf(fmaxf(qpos[qg * 3 + 2], 0.f), 1.f);
    unsigned m = (mort7((unsigned)(x * 127.f)) << 2)
               | (mort7((unsigned)(y * 127.f)) << 1)
               |  mort7((unsigned)(z * 127.f));          // 21 bits
    unsigned bkt = ((unsigned)(i >> 10) << 7) | (m >> 14);
    myb[r] = bkt;
    atomicAdd(&cnt[bkt], 1u);
  }
  __syncthreads();
  if (t == 0) {
    unsigned s = 0;
    for (int k = 0; k < 256; k++) { base[k] = s; s += cnt[k]; }
  }
  __syncthreads();
  #pragma unroll
  for (int r = 0; r < 2; r++) {
    int i = t + r * 1024;
    unsigned pos = atomicAdd(&base[myb[r]], 1u);
    perm[(size_t)pair * PAIR_Q + pos] = (unsigned)i;
  }
}

// ---------------------------------------------------------------------------
// Bilinear helpers (channel-last plane)
// ---------------------------------------------------------------------------
__device__ __forceinline__ float sample_plane(const float* __restrict__ p,
                                              float u, float v) {
  float x = fminf(fmaxf(u, 0.f), 1.f) * (float)(H - 1);
  float y = fminf(fmaxf(v, 0.f), 1.f) * (float)(H - 1);
  float xf = floorf(x), yf = floorf(y);
  int x0 = (int)xf, y0 = (int)yf;
  float wx = x - xf, wy = y - yf;
  int dx = (x0 < H - 1) ? FD : 0;
  int dy = (y0 < H - 1) ? H * FD : 0;
  int i00 = (y0 * H + x0) * FD;
  float f00 = p[i00], f01 = p[i00 + dx], f10 = p[i00 + dy], f11 = p[i00 + dy + dx];
  float a = f00 + wx * (f01 - f00);
  float b = f10 + wx * (f11 - f10);
  return a + wy * (b - a);
}

__device__ __forceinline__ void setup_samp(int* si, float* sw, float u, float v) {
  float x = fminf(fmaxf(u, 0.f), 1.f) * (float)(H - 1);
  float y = fminf(fmaxf(v, 0.f), 1.f) * (float)(H - 1);
  float xf = floorf(x), yf = floorf(y);
  int x0 = (int)xf, y0 = (int)yf;
  float wx = x - xf, wy = y - yf;
  si[0] = (y0 * H + x0) * FD;
  si[1] = (x0 < H - 1) ? FD : 0;
  si[2] = (y0 < H - 1) ? H * FD : 0;
  sw[0] = (1.f - wy) * (1.f - wx);
  sw[1] = (1.f - wy) * wx;
  sw[2] = wy * (1.f - wx);
  sw[3] = wy * wx;
}

// ---------------------------------------------------------------------------
// K2: per 4-query tile: feature sampling + offsets/aux + q-projection + qk.
// qk[q][c] = sum_e q_scaled[e] * w_k[c][e];  (q . b_k cancels in softmax)
// QTF=4 -> 512 blocks -> 2 blocks/CU (was 1/CU at QT=8: latency-exposed).
// ---------------------------------------------------------------------------
__global__ __launch_bounds__(256) void featk(
    const float* __restrict__ qpos, const float* __restrict__ planesT,
    const float* __restrict__ w_off, const float* __restrict__ b_off,
    const float* __restrict__ w_q, const float* __restrict__ b_q,
    const float* __restrict__ w_k,
    float* __restrict__ feat, float* __restrict__ aux, float* __restrict__ qk,
    int b0)
{
  const int tid = threadIdx.x;
  const int q0l = blockIdx.x * QTF;         // local query base in pair
  const int bl = q0l >> 10;                 // local batch
  __shared__ float s_feat[QTF * 260];
  __shared__ float s_q[QTF * 68];

  const float* Pxz = planesT + 0 * (size_t)PPLANE + (size_t)bl * BATCH_ELEMS + tid;
  const float* Pxy = planesT + 1 * (size_t)PPLANE + (size_t)bl * BATCH_ELEMS + tid;
  const float* Pyz = planesT + 2 * (size_t)PPLANE + (size_t)bl * BATCH_ELEMS + tid;

  for (int qs = 0; qs < QTF; qs++) {
    size_t qg = (size_t)b0 * NS + q0l + qs; // global query for qpos
    float px = qpos[qg * 3 + 0], py = qpos[qg * 3 + 1], pz = qpos[qg * 3 + 2];
    float f = sample_plane(Pxz, px, pz) + sample_plane(Pxy, px, py)
            + sample_plane(Pyz, py, pz);
    s_feat[qs * 260 + tid] = f;
    feat[(size_t)(q0l + qs) * FD + tid] = f;
  }
  __syncthreads();

  // offsets -> aux. thread t<192: half=t/96 handles 2 queries for column j.
  if (tid < 192) {
    int half = tid / 96, j = tid - half * 96;
    float acc[2];
    float bj = b_off[j];
    acc[0] = bj; acc[1] = bj;
    for (int c = 0; c < FD; c++) {
      float wv = w_off[c * 96 + j];
      #pragma unroll
      for (int k = 0; k < 2; k++)
        acc[k] = fmaf(s_feat[(half * 2 + k) * 260 + c], wv, acc[k]);
    }
    int d = j % 3;
    #pragma unroll
    for (int k = 0; k < 2; k++) {
      int qs = half * 2 + k;
      size_t qg = (size_t)b0 * NS + q0l + qs;
      aux[(size_t)(q0l + qs) * 96 + j] = acc[k] + qpos[qg * 3 + d];
    }
  }
  // q projection (scaled by sqrt(E)=8); wave g handles query g
  {
    int e = tid & 63, g = tid >> 6;
    float a = b_q[e];
    for (int c = 0; c < FD; c++)
      a = fmaf(s_feat[g * 260 + c], w_q[c * EDIM + e], a);
    s_q[g * 68 + e] = a * 8.0f;
  }
  __syncthreads();
  // qk: thread owns channel tid; w_k row contiguous (float4)
  {
    float acc[QTF];
    #pragma unroll
    for (int qs = 0; qs < QTF; qs++) acc[qs] = 0.f;
    const float4* wk4 = reinterpret_cast<const float4*>(w_k + (size_t)tid * EDIM);
    for (int e4 = 0; e4 < EDIM / 4; e4++) {
      float4 wv = wk4[e4];
      int e = e4 * 4;
      #pragma unroll
      for (int qs = 0; qs < QTF; qs++) {
        acc[qs] = fmaf(s_q[qs * 68 + e + 0], wv.x, acc[qs]);
        acc[qs] = fmaf(s_q[qs * 68 + e + 1], wv.y, acc[qs]);
        acc[qs] = fmaf(s_q[qs * 68 + e + 2], wv.z, acc[qs]);
        acc[qs] = fmaf(s_q[qs * 68 + e + 3], wv.w, acc[qs]);
      }
    }
    #pragma unroll
    for (int qs = 0; qs < QTF; qs++)
      qk[(size_t)(q0l + qs) * FD + tid] = acc[qs];
  }
}

// ---------------------------------------------------------------------------
// K3 (hot): 2 Morton-adjacent queries per block. Wave w -> query (w>>1),
// heads {w&1, (w&1)+2}. Head h only attends points p ≡ h (mod NH), so the
// wave samples exactly the 16 points it later aggregates: af stays in
// 16 bf16 VGPRs (sim path stays fp32 pre-pack). sim is made wave-uniform by
// the full butterfly, so softmax is in-register scalar math: no s_af/s_sim,
// ZERO barriers after setup. LDS 5.4 KB; launch_bounds(256,6) -> 6 blocks/CU
// (24 waves/CU vs 16 before: attnk was latency-bound at VALUBusy 11%).
// ---------------------------------------------------------------------------
__global__ __launch_bounds__(256, 6) void attnk(
    const float* __restrict__ planesT, const float* __restrict__ aux,
    const float* __restrict__ qk, const unsigned* __restrict__ perm,
    float* __restrict__ wf)
{
  const int tid = threadIdx.x, lane = tid & 63, w = tid >> 6;
  const int bid = blockIdx.x;                 // 0..1023
  const int j = ((bid & 7) << 7) | (bid >> 3);
  const int c4 = lane * 4;

  __shared__ int   s_si[2][96][3];
  __shared__ float s_sw[2][96][4];

  if (tid < 192) {
    int qi_s = tid / 96, r = tid - qi_s * 96;
    int p = r / 3, pl = r - p * 3;
    int qq = (int)perm[2 * j + qi_s];
    float ax = aux[(size_t)qq * 96 + p * 3 + 0];
    float ay = aux[(size_t)qq * 96 + p * 3 + 1];
    float az = aux[(size_t)qq * 96 + p * 3 + 2];
    float u = (pl == 2) ? ay : ax;   // pl0:(ax,az) pl1:(ax,ay) pl2:(ay,az)
    float v = (pl == 1) ? ay : az;
    setup_samp(s_si[qi_s][r], s_sw[qi_s][r], u, v);
  }

  const int qi = w >> 1;                      // this wave's query slot
  const int h0 = w & 1;                       // heads h0 and h0+2
  const int qw = (int)perm[2 * j + qi];
  const int blw = qw >> 10;
  float4 qk4 = *(const float4*)(qk + (size_t)qw * FD + c4);
  const float* P0 = planesT + 0 * (size_t)PPLANE + (size_t)blw * BATCH_ELEMS + c4;
  const float* P1 = planesT + 1 * (size_t)PPLANE + (size_t)blw * BATCH_ELEMS + c4;
  const float* P2 = planesT + 2 * (size_t)PPLANE + (size_t)blw * BATCH_ELEMS + c4;
  __syncthreads();

  #pragma unroll
  for (int hi = 0; hi < 2; hi++) {
    const int h = h0 + 2 * hi;
    ushort4 af16[SP3];                        // bf16 af, 16 VGPRs
    float sim[SP3];                           // wave-uniform sims
    #pragma unroll 2
    for (int jj = 0; jj < SP3; jj++) {
      const int p = jj * NH + h;
      float4 a; a.x = 0.f; a.y = 0.f; a.z = 0.f; a.w = 0.f;
      #pragma unroll
      for (int pl = 0; pl < 3; pl++) {
        const float* P = pl == 0 ? P0 : (pl == 1 ? P1 : P2);
        int i00 = s_si[qi][p * 3 + pl][0];
        int dxo = s_si[qi][p * 3 + pl][1];
        int dyo = s_si[qi][p * 3 + pl][2];
        float w0 = s_sw[qi][p * 3 + pl][0], w1 = s_sw[qi][p * 3 + pl][1];
        float w2 = s_sw[qi][p * 3 + pl][2], w3 = s_sw[qi][p * 3 + pl][3];
        float4 f00 = *(const float4*)(P + i00);
        float4 f01 = *(const float4*)(P + i00 + dxo);
        float4 f10 = *(const float4*)(P + i00 + dyo);
        float4 f11 = *(const float4*)(P + i00 + dyo + dxo);
        a.x = fmaf(w0, f00.x, fmaf(w1, f01.x, fmaf(w2, f10.x, fmaf(w3, f11.x, a.x))));
        a.y = fmaf(w0, f00.y, fmaf(w1, f01.y, fmaf(w2, f10.y, fmaf(w3, f11.y, a.y))));
        a.z = fmaf(w0, f00.z, fmaf(w1, f01.z, fmaf(w2, f10.z, fmaf(w3, f11.z, a.z))));
        a.w = fmaf(w0, f00.w, fmaf(w1, f01.w, fmaf(w2, f10.w, fmaf(w3, f11.w, a.w))));
      }
      ushort4 hh;
      hh.x = f2bf(a.x); hh.y = f2bf(a.y); hh.z = f2bf(a.z); hh.w = f2bf(a.w);
      af16[jj] = hh;
      float t = fmaf(qk4.x, a.x, fmaf(qk4.y, a.y, fmaf(qk4.z, a.z, qk4.w * a.w)));
      #pragma unroll
      for (int o = 32; o >= 1; o >>= 1) t += __shfl_xor(t, o, 64);
      sim[jj] = t;                            // uniform across lanes
    }
    // softmax over jj (uniform scalar math in every lane; no LDS, no barrier)
    float m = -1e30f;
    #pragma unroll
    for (int jj = 0; jj < SP3; jj++) m = fmaxf(m, sim[jj]);
    float sum = 0.f;
    #pragma unroll
    for (int jj = 0; jj < SP3; jj++) { sim[jj] = __expf(sim[jj] - m); sum += sim[jj]; }
    float inv = 1.0f / sum;
    float4 r; r.x = 0.f; r.y = 0.f; r.z = 0.f; r.w = 0.f;
    #pragma unroll
    for (int jj = 0; jj < SP3; jj++) {
      float av = sim[jj] * inv;
      ushort4 hv = af16[jj];
      r.x = fmaf(av, bf2f(hv.x), r.x);
      r.y = fmaf(av, bf2f(hv.y), r.y);
      r.z = fmaf(av, bf2f(hv.z), r.z);
      r.w = fmaf(av, bf2f(hv.w), r.w);
    }
    *(float4*)(wf + ((size_t)qw * NH + h) * FD + c4) = r;
  }
}

// ---------------------------------------------------------------------------
// K4: epilogue per 4-query tile: o = per-head wf@w_v + b_v (w_v in LDS),
// then out = o@w_out + b_out + feat (w_out streamed once per block).
// QTE=4 -> 512 blocks -> 2 blocks/CU (LDS 68 KB still allows 2).
// ---------------------------------------------------------------------------
__global__ __launch_bounds__(256) void epik(
    const float* __restrict__ wf, const float* __restrict__ feat,
    const float* __restrict__ w_v, const float* __restrict__ b_v,
    const float* __restrict__ w_out, const float* __restrict__ b_out,
    float* __restrict__ out, int b0)
{
  const int tid = threadIdx.x;
  const int q0l = blockIdx.x * QTE;
  __shared__ float s_wv[FD * EDIM];   // 64 KB, [c][e]
  __shared__ float s_o[QTE * 257];

  {
    const float4* src4 = (const float4*)w_v;
    float4* dst4 = (float4*)s_wv;
    #pragma unroll
    for (int i = 0; i < (FD * EDIM / 4) / 256; i++)
      dst4[tid + 256 * i] = src4[tid + 256 * i];
  }
  __syncthreads();

  { // phase A: o[qs][h*64+e]
    int h = tid >> 6, e = tid & 63;
    float acc[QTE];
    float bv = b_v[e];
    #pragma unroll
    for (int qs = 0; qs < QTE; qs++) acc[qs] = bv;
    const float* wrow = wf + ((size_t)q0l * NH + h) * FD;
    for (int c = 0; c < FD; c++) {
      float wv = s_wv[c * EDIM + e];
      #pragma unroll
      for (int qs = 0; qs < QTE; qs++)
        acc[qs] = fmaf(wrow[(size_t)qs * NH * FD + c], wv, acc[qs]);
    }
    #pragma unroll
    for (int qs = 0; qs < QTE; qs++) s_o[qs * 257 + h * EDIM + e] = acc[qs];
  }
  __syncthreads();

  { // phase B: out[q][d] = sum_c o[q][c] w_out[c][d] + b_out[d] + feat[q][d]
    float r[QTE];
    float bo = b_out[tid];
    #pragma unroll
    for (int qs = 0; qs < QTE; qs++) r[qs] = bo;
    for (int c = 0; c < FD; c++) {
      float wv = w_out[(size_t)c * FD + tid];
      #pragma unroll
      for (int qs = 0; qs < QTE; qs++)
        r[qs] = fmaf(s_o[qs * 257 + c], wv, r[qs]);
    }
    #pragma unroll
    for (int qs = 0; qs < QTE; qs++)
      out[((size_t)b0 * NS + q0l + qs) * FD + tid]
          = r[qs] + feat[(size_t)(q0l + qs) * FD + tid];
  }
}

// ---------------------------------------------------------------------------
extern "C" void kernel_launch(void* const* d_in, const int* in_sizes, int n_in,
                              void* d_out, int out_size, void* d_ws, size_t ws_size,
                              hipStream_t stream) {
  const float* qp    = (const float*)d_in[0];
  const float* cxz   = (const float*)d_in[1];
  const float* cxy   = (const float*)d_in[2];
  const float* cyz   = (const float*)d_in[3];
  const float* w_off = (const float*)d_in[4];
  const float* b_off = (const float*)d_in[5];
  const float* w_q   = (const float*)d_in[6];
  const float* b_q   = (const float*)d_in[7];
  const float* w_k   = (const float*)d_in[8];
  const float* b_k   = (const float*)d_in[9];   (void)b_k; // cancels in softmax
  const float* w_v   = (const float*)d_in[10];
  const float* b_v   = (const float*)d_in[11];
  const float* w_out = (const float*)d_in[12];
  const float* b_out = (const float*)d_in[13];
  float* out = (float*)d_out;
  (void)in_sizes; (void)n_in; (void)out_size; (void)ws_size;

  float* ws      = (float*)d_ws;
  float* planesT = ws + WS_PLANES;
  float* feat    = ws + WS_FEAT;
  float* qk      = ws + WS_QK;
  float* aux     = ws + WS_AUX;
  float* wf      = ws + WS_WF;
  unsigned* perm = (unsigned*)(ws + WS_PERM);

  hipLaunchKernelGGL(sortk, dim3(BS / PAIR_B), dim3(1024), 0, stream, qp, perm);

  for (int pair = 0; pair < BS / PAIR_B; ++pair) {
    int b0 = pair * PAIR_B;
    hipLaunchKernelGGL(tpk2, dim3(3 * PAIR_B * 512), dim3(256), 0, stream,
                       cxz, cxy, cyz, planesT, b0);
    hipLaunchKernelGGL(featk, dim3(PAIR_Q / QTF), dim3(256), 0, stream,
                       qp, planesT, w_off, b_off, w_q, b_q, w_k,
                       feat, aux, qk, b0);
    hipLaunchKernelGGL(attnk, dim3(PAIR_Q / 2), dim3(256), 0, stream,
                       planesT, aux, qk, perm + (size_t)pair * PAIR_Q, wf);
    hipLaunchKernelGGL(epik, dim3(PAIR_Q / QTE), dim3(256), 0, stream,
                       wf, feat, w_v, b_v, w_out, b_out, out, b0);
  }
}

// Round 2
// 514.468 us; speedup vs baseline: 1.0474x; 1.0334x over previous
//
#include <hip/hip_runtime.h>
#include <math.h>

// Problem constants
#define FD   256
#define NH   4
#define SP3  8
#define NP   32          // SP3*NH aux points per query
#define EDIM 64          // FD/NH
#define H    128
#define NS   1024
#define BS   4
#define QTF  4           // queries per featk block (512 blocks -> 2/CU)
#define QTE  4           // queries per epik block  (512 blocks -> 2/CU)

#define TEX         (H*H)              // 16384 texels per (plane,b)
#define BATCH_ELEMS (TEX*FD)           // 4,194,304 floats
#define PAIR_B      2                  // batches processed per pass
#define PAIR_Q      (PAIR_B*NS)        // 2048 queries per pass
#define PPLANE      (PAIR_B*BATCH_ELEMS) // per-plane elems in pair buffer

// ---- workspace layout (float offsets). Total ~114.05 MB.
// ws_size proven >= 114 MB (rounds 3/5 passed); 228 MB overflowed (round 2).
#define WS_PLANES 0
#define WS_FEAT   (3*PPLANE)                       // [2048][256]
#define WS_QK     (WS_FEAT + PAIR_Q*FD)            // [2048][256]
#define WS_AUX    (WS_QK   + PAIR_Q*FD)            // [2048][96]
#define WS_WF     (WS_AUX  + PAIR_Q*NP*3)          // [2048][4][256]
#define WS_PERM   (WS_WF   + PAIR_Q*NH*FD)         // [2 pairs][2048] uint

// bf16 helpers (round-to-nearest-even). Used ONLY on the wf path (af after
// the fp32 sim dot) — sim-path quantization is amplified ~176x and is fatal.
__device__ __forceinline__ unsigned short f2bf(float f) {
  unsigned b = __float_as_uint(f);
  return (unsigned short)((b + 0x7FFFu + ((b >> 16) & 1u)) >> 16);
}
__device__ __forceinline__ float bf2f(unsigned short u) {
  return __uint_as_float(((unsigned)u) << 16);
}

// ---------------------------------------------------------------------------
// K1: transpose planes [B,C,H,W] -> [b-pair][H*W,C] (channel-last).
// 32-texel x 256-channel tiles; LDS 33 KB -> 4 blocks/CU.
// ---------------------------------------------------------------------------
__global__ __launch_bounds__(256) void tpk2(
    const float* __restrict__ xz, const float* __restrict__ xy,
    const float* __restrict__ yz, float* __restrict__ dstAll, int b0)
{
  int bid = blockIdx.x;
  int tT = bid & 511; bid >>= 9;     // 512 texel-tiles of 32
  int bl = bid & 1;   bid >>= 1;     // local batch in pair
  int pl = bid;                      // plane
  const float* src = pl == 0 ? xz : (pl == 1 ? xy : yz);
  float* dst = dstAll + (size_t)pl * PPLANE + (size_t)bl * BATCH_ELEMS;
  int b = b0 + bl;

  __shared__ float T[32 * 260];      // T[texel][channel], stride 260
  int lane = threadIdx.x & 63, w = threadIdx.x >> 6;
  int tex4 = (lane & 7) * 4;         // 0,4,..,28
  int csub = lane >> 3;              // 0..7

  const float* sbase = src + (size_t)b * FD * TEX + tT * 32;
  #pragma unroll
  for (int i = 0; i < 8; i++) {
    int c = i * 32 + w * 8 + csub;   // covers 0..255
    float4 v = *(const float4*)(sbase + (size_t)c * TEX + tex4);
    T[(tex4 + 0) * 260 + c] = v.x;
    T[(tex4 + 1) * 260 + c] = v.y;
    T[(tex4 + 2) * 260 + c] = v.z;
    T[(tex4 + 3) * 260 + c] = v.w;
  }
  __syncthreads();
  #pragma unroll
  for (int i = 0; i < 8; i++) {
    int t = w * 8 + i;
    float4 v = *(const float4*)(&T[t * 260 + lane * 4]);
    *(float4*)(dst + (size_t)(tT * 32 + t) * FD + lane * 4) = v;  // 1KB/wave
  }
}

// ---------------------------------------------------------------------------
// K1b: counting-sort the pair's 2048 queries into 256 buckets =
// (batch<<7)|top-7-Morton-bits. Any permutation is correctness-neutral;
// bucket granularity (~8 queries/cell) is all the locality we measured to
// matter. One block per pair, O(n), ~3 barriers.
// ---------------------------------------------------------------------------
__device__ __forceinline__ unsigned mort7(unsigned v) {   // 7 bits -> every 3rd
  unsigned r = 0;
  #pragma unroll
  for (int i = 0; i < 7; i++) r |= ((v >> i) & 1u) << (3 * i);
  return r;
}

__global__ __launch_bounds__(1024) void sortk(
    const float* __restrict__ qpos, unsigned* __restrict__ perm)
{
  const int pair = blockIdx.x;
  const int b0 = pair * PAIR_B;
  const int t = threadIdx.x;
  __shared__ unsigned cnt[256];
  __shared__ unsigned base[256];
  if (t < 256) cnt[t] = 0;
  __syncthreads();
  unsigned myb[2];
  #pragma unroll
  for (int r = 0; r < 2; r++) {
    int i = t + r * 1024;
    size_t qg = (size_t)b0 * NS + i;
    float x = fminf(fmaxf(qpos[qg * 3 + 0], 0.f), 1.f);
    float y = fminf(fmaxf(qpos[qg * 3 + 1], 0.f), 1.f);
    float z = fminf(fmaxf(qpos[qg * 3 + 2], 0.f), 1.f);
    unsigned m = (mort7((unsigned)(x * 127.f)) << 2)
               | (mort7((unsigned)(y * 127.f)) << 1)
               |  mort7((unsigned)(z * 127.f));          // 21 bits
    unsigned bkt = ((unsigned)(i >> 10) << 7) | (m >> 14);
    myb[r] = bkt;
    atomicAdd(&cnt[bkt], 1u);
  }
  __syncthreads();
  if (t == 0) {
    unsigned s = 0;
    for (int k = 0; k < 256; k++) { base[k] = s; s += cnt[k]; }
  }
  __syncthreads();
  #pragma unroll
  for (int r = 0; r < 2; r++) {
    int i = t + r * 1024;
    unsigned pos = atomicAdd(&base[myb[r]], 1u);
    perm[(size_t)pair * PAIR_Q + pos] = (unsigned)i;
  }
}

// ---------------------------------------------------------------------------
// Bilinear helpers (channel-last plane)
// ---------------------------------------------------------------------------
__device__ __forceinline__ float sample_plane(const float* __restrict__ p,
                                              float u, float v) {
  float x = fminf(fmaxf(u, 0.f), 1.f) * (float)(H - 1);
  float y = fminf(fmaxf(v, 0.f), 1.f) * (float)(H - 1);
  float xf = floorf(x), yf = floorf(y);
  int x0 = (int)xf, y0 = (int)yf;
  float wx = x - xf, wy = y - yf;
  int dx = (x0 < H - 1) ? FD : 0;
  int dy = (y0 < H - 1) ? H * FD : 0;
  int i00 = (y0 * H + x0) * FD;
  float f00 = p[i00], f01 = p[i00 + dx], f10 = p[i00 + dy], f11 = p[i00 + dy + dx];
  float a = f00 + wx * (f01 - f00);
  float b = f10 + wx * (f11 - f10);
  return a + wy * (b - a);
}

__device__ __forceinline__ void setup_samp(int* si, float* sw, float u, float v) {
  float x = fminf(fmaxf(u, 0.f), 1.f) * (float)(H - 1);
  float y = fminf(fmaxf(v, 0.f), 1.f) * (float)(H - 1);
  float xf = floorf(x), yf = floorf(y);
  int x0 = (int)xf, y0 = (int)yf;
  float wx = x - xf, wy = y - yf;
  si[0] = (y0 * H + x0) * FD;
  si[1] = (x0 < H - 1) ? FD : 0;
  si[2] = (y0 < H - 1) ? H * FD : 0;
  sw[0] = (1.f - wy) * (1.f - wx);
  sw[1] = (1.f - wy) * wx;
  sw[2] = wy * (1.f - wx);
  sw[3] = wy * wx;
}

// ---------------------------------------------------------------------------
// K2: per 4-query tile: feature sampling + offsets/aux + q-projection + qk.
// qk[q][c] = sum_e q_scaled[e] * w_k[c][e];  (q . b_k cancels in softmax)
// QTF=4 -> 512 blocks -> 2 blocks/CU (was 1/CU at QT=8: latency-exposed).
// ---------------------------------------------------------------------------
__global__ __launch_bounds__(256) void featk(
    const float* __restrict__ qpos, const float* __restrict__ planesT,
    const float* __restrict__ w_off, const float* __restrict__ b_off,
    const float* __restrict__ w_q, const float* __restrict__ b_q,
    const float* __restrict__ w_k,
    float* __restrict__ feat, float* __restrict__ aux, float* __restrict__ qk,
    int b0)
{
  const int tid = threadIdx.x;
  const int q0l = blockIdx.x * QTF;         // local query base in pair
  const int bl = q0l >> 10;                 // local batch
  __shared__ float s_feat[QTF * 260];
  __shared__ float s_q[QTF * 68];

  const float* Pxz = planesT + 0 * (size_t)PPLANE + (size_t)bl * BATCH_ELEMS + tid;
  const float* Pxy = planesT + 1 * (size_t)PPLANE + (size_t)bl * BATCH_ELEMS + tid;
  const float* Pyz = planesT + 2 * (size_t)PPLANE + (size_t)bl * BATCH_ELEMS + tid;

  for (int qs = 0; qs < QTF; qs++) {
    size_t qg = (size_t)b0 * NS + q0l + qs; // global query for qpos
    float px = qpos[qg * 3 + 0], py = qpos[qg * 3 + 1], pz = qpos[qg * 3 + 2];
    float f = sample_plane(Pxz, px, pz) + sample_plane(Pxy, px, py)
            + sample_plane(Pyz, py, pz);
    s_feat[qs * 260 + tid] = f;
    feat[(size_t)(q0l + qs) * FD + tid] = f;
  }
  __syncthreads();

  // offsets -> aux. thread t<192: half=t/96 handles 2 queries for column j.
  if (tid < 192) {
    int half = tid / 96, j = tid - half * 96;
    float acc[2];
    float bj = b_off[j];
    acc[0] = bj; acc[1] = bj;
    for (int c = 0; c < FD; c++) {
      float wv = w_off[c * 96 + j];
      #pragma unroll
      for (int k = 0; k < 2; k++)
        acc[k] = fmaf(s_feat[(half * 2 + k) * 260 + c], wv, acc[k]);
    }
    int d = j % 3;
    #pragma unroll
    for (int k = 0; k < 2; k++) {
      int qs = half * 2 + k;
      size_t qg = (size_t)b0 * NS + q0l + qs;
      aux[(size_t)(q0l + qs) * 96 + j] = acc[k] + qpos[qg * 3 + d];
    }
  }
  // q projection (scaled by sqrt(E)=8); wave g handles query g
  {
    int e = tid & 63, g = tid >> 6;
    float a = b_q[e];
    for (int c = 0; c < FD; c++)
      a = fmaf(s_feat[g * 260 + c], w_q[c * EDIM + e], a);
    s_q[g * 68 + e] = a * 8.0f;
  }
  __syncthreads();
  // qk: thread owns channel tid; w_k row contiguous (float4)
  {
    float acc[QTF];
    #pragma unroll
    for (int qs = 0; qs < QTF; qs++) acc[qs] = 0.f;
    const float4* wk4 = reinterpret_cast<const float4*>(w_k + (size_t)tid * EDIM);
    for (int e4 = 0; e4 < EDIM / 4; e4++) {
      float4 wv = wk4[e4];
      int e = e4 * 4;
      #pragma unroll
      for (int qs = 0; qs < QTF; qs++) {
        acc[qs] = fmaf(s_q[qs * 68 + e + 0], wv.x, acc[qs]);
        acc[qs] = fmaf(s_q[qs * 68 + e + 1], wv.y, acc[qs]);
        acc[qs] = fmaf(s_q[qs * 68 + e + 2], wv.z, acc[qs]);
        acc[qs] = fmaf(s_q[qs * 68 + e + 3], wv.w, acc[qs]);
      }
    }
    #pragma unroll
    for (int qs = 0; qs < QTF; qs++)
      qk[(size_t)(q0l + qs) * FD + tid] = acc[qs];
  }
}

// ---------------------------------------------------------------------------
// K3 (hot): 2 Morton-adjacent queries per block. Wave w -> query (w>>1),
// heads {w&1, (w&1)+2}. Head h only attends points p ≡ h (mod NH), so the
// wave samples exactly the 16 points it later aggregates.
// ROUND-2 FIX: the jj loop is now FULLY unrolled — round 1's `unroll 2`
// left af16[jj]/sim[jj] runtime-indexed -> scratch spill (VGPR=40,
// WRITE_SIZE 8->41 MB of scratch round-trips, attnk 84->91 us). Static
// indexing keeps af/sim in VGPRs; launch_bounds(256,4) lifts the VGPR cap
// to 128 (grid is 1024 = 4 blocks/CU, so >4 waves/EU is unreachable anyway)
// so the compiler can keep many of the 96 gather loads per wave in flight.
// ---------------------------------------------------------------------------
__global__ __launch_bounds__(256, 4) void attnk(
    const float* __restrict__ planesT, const float* __restrict__ aux,
    const float* __restrict__ qk, const unsigned* __restrict__ perm,
    float* __restrict__ wf)
{
  const int tid = threadIdx.x, lane = tid & 63, w = tid >> 6;
  const int bid = blockIdx.x;                 // 0..1023
  const int j = ((bid & 7) << 7) | (bid >> 3);
  const int c4 = lane * 4;

  __shared__ int   s_si[2][96][3];
  __shared__ float s_sw[2][96][4];

  if (tid < 192) {
    int qi_s = tid / 96, r = tid - qi_s * 96;
    int p = r / 3, pl = r - p * 3;
    int qq = (int)perm[2 * j + qi_s];
    float ax = aux[(size_t)qq * 96 + p * 3 + 0];
    float ay = aux[(size_t)qq * 96 + p * 3 + 1];
    float az = aux[(size_t)qq * 96 + p * 3 + 2];
    float u = (pl == 2) ? ay : ax;   // pl0:(ax,az) pl1:(ax,ay) pl2:(ay,az)
    float v = (pl == 1) ? ay : az;
    setup_samp(s_si[qi_s][r], s_sw[qi_s][r], u, v);
  }

  const int qi = w >> 1;                      // this wave's query slot
  const int h0 = w & 1;                       // heads h0 and h0+2
  const int qw = (int)perm[2 * j + qi];
  const int blw = qw >> 10;
  float4 qk4 = *(const float4*)(qk + (size_t)qw * FD + c4);
  const float* P0 = planesT + 0 * (size_t)PPLANE + (size_t)blw * BATCH_ELEMS + c4;
  const float* P1 = planesT + 1 * (size_t)PPLANE + (size_t)blw * BATCH_ELEMS + c4;
  const float* P2 = planesT + 2 * (size_t)PPLANE + (size_t)blw * BATCH_ELEMS + c4;
  __syncthreads();

  #pragma unroll
  for (int hi = 0; hi < 2; hi++) {
    const int h = h0 + 2 * hi;
    ushort4 af16[SP3];                        // bf16 af, 16 VGPRs (static idx)
    float sim[SP3];                           // wave-uniform sims (static idx)
    #pragma unroll
    for (int jj = 0; jj < SP3; jj++) {
      const int p = jj * NH + h;
      float4 a; a.x = 0.f; a.y = 0.f; a.z = 0.f; a.w = 0.f;
      #pragma unroll
      for (int pl = 0; pl < 3; pl++) {
        const float* P = pl == 0 ? P0 : (pl == 1 ? P1 : P2);
        int i00 = s_si[qi][p * 3 + pl][0];
        int dxo = s_si[qi][p * 3 + pl][1];
        int dyo = s_si[qi][p * 3 + pl][2];
        float w0 = s_sw[qi][p * 3 + pl][0], w1 = s_sw[qi][p * 3 + pl][1];
        float w2 = s_sw[qi][p * 3 + pl][2], w3 = s_sw[qi][p * 3 + pl][3];
        float4 f00 = *(const float4*)(P + i00);
        float4 f01 = *(const float4*)(P + i00 + dxo);
        float4 f10 = *(const float4*)(P + i00 + dyo);
        float4 f11 = *(const float4*)(P + i00 + dyo + dxo);
        a.x = fmaf(w0, f00.x, fmaf(w1, f01.x, fmaf(w2, f10.x, fmaf(w3, f11.x, a.x))));
        a.y = fmaf(w0, f00.y, fmaf(w1, f01.y, fmaf(w2, f10.y, fmaf(w3, f11.y, a.y))));
        a.z = fmaf(w0, f00.z, fmaf(w1, f01.z, fmaf(w2, f10.z, fmaf(w3, f11.z, a.z))));
        a.w = fmaf(w0, f00.w, fmaf(w1, f01.w, fmaf(w2, f10.w, fmaf(w3, f11.w, a.w))));
      }
      ushort4 hh;
      hh.x = f2bf(a.x); hh.y = f2bf(a.y); hh.z = f2bf(a.z); hh.w = f2bf(a.w);
      af16[jj] = hh;
      float t = fmaf(qk4.x, a.x, fmaf(qk4.y, a.y, fmaf(qk4.z, a.z, qk4.w * a.w)));
      #pragma unroll
      for (int o = 32; o >= 1; o >>= 1) t += __shfl_xor(t, o, 64);
      sim[jj] = t;                            // uniform across lanes
    }
    // softmax over jj (uniform scalar math in every lane; no LDS, no barrier)
    float m = -1e30f;
    #pragma unroll
    for (int jj = 0; jj < SP3; jj++) m = fmaxf(m, sim[jj]);
    float sum = 0.f;
    #pragma unroll
    for (int jj = 0; jj < SP3; jj++) { sim[jj] = __expf(sim[jj] - m); sum += sim[jj]; }
    float inv = 1.0f / sum;
    float4 r; r.x = 0.f; r.y = 0.f; r.z = 0.f; r.w = 0.f;
    #pragma unroll
    for (int jj = 0; jj < SP3; jj++) {
      float av = sim[jj] * inv;
      ushort4 hv = af16[jj];
      r.x = fmaf(av, bf2f(hv.x), r.x);
      r.y = fmaf(av, bf2f(hv.y), r.y);
      r.z = fmaf(av, bf2f(hv.z), r.z);
      r.w = fmaf(av, bf2f(hv.w), r.w);
    }
    *(float4*)(wf + ((size_t)qw * NH + h) * FD + c4) = r;
  }
}

// ---------------------------------------------------------------------------
// K4: epilogue per 4-query tile: o = per-head wf@w_v + b_v (w_v in LDS),
// then out = o@w_out + b_out + feat (w_out streamed once per block).
// QTE=4 -> 512 blocks -> 2 blocks/CU (LDS 68 KB still allows 2).
// ---------------------------------------------------------------------------
__global__ __launch_bounds__(256) void epik(
    const float* __restrict__ wf, const float* __restrict__ feat,
    const float* __restrict__ w_v, const float* __restrict__ b_v,
    const float* __restrict__ w_out, const float* __restrict__ b_out,
    float* __restrict__ out, int b0)
{
  const int tid = threadIdx.x;
  const int q0l = blockIdx.x * QTE;
  __shared__ float s_wv[FD * EDIM];   // 64 KB, [c][e]
  __shared__ float s_o[QTE * 257];

  {
    const float4* src4 = (const float4*)w_v;
    float4* dst4 = (float4*)s_wv;
    #pragma unroll
    for (int i = 0; i < (FD * EDIM / 4) / 256; i++)
      dst4[tid + 256 * i] = src4[tid + 256 * i];
  }
  __syncthreads();

  { // phase A: o[qs][h*64+e]
    int h = tid >> 6, e = tid & 63;
    float acc[QTE];
    float bv = b_v[e];
    #pragma unroll
    for (int qs = 0; qs < QTE; qs++) acc[qs] = bv;
    const float* wrow = wf + ((size_t)q0l * NH + h) * FD;
    for (int c = 0; c < FD; c++) {
      float wv = s_wv[c * EDIM + e];
      #pragma unroll
      for (int qs = 0; qs < QTE; qs++)
        acc[qs] = fmaf(wrow[(size_t)qs * NH * FD + c], wv, acc[qs]);
    }
    #pragma unroll
    for (int qs = 0; qs < QTE; qs++) s_o[qs * 257 + h * EDIM + e] = acc[qs];
  }
  __syncthreads();

  { // phase B: out[q][d] = sum_c o[q][c] w_out[c][d] + b_out[d] + feat[q][d]
    float r[QTE];
    float bo = b_out[tid];
    #pragma unroll
    for (int qs = 0; qs < QTE; qs++) r[qs] = bo;
    for (int c = 0; c < FD; c++) {
      float wv = w_out[(size_t)c * FD + tid];
      #pragma unroll
      for (int qs = 0; qs < QTE; qs++)
        r[qs] = fmaf(s_o[qs * 257 + c], wv, r[qs]);
    }
    #pragma unroll
    for (int qs = 0; qs < QTE; qs++)
      out[((size_t)b0 * NS + q0l + qs) * FD + tid]
          = r[qs] + feat[(size_t)(q0l + qs) * FD + tid];
  }
}

// ---------------------------------------------------------------------------
extern "C" void kernel_launch(void* const* d_in, const int* in_sizes, int n_in,
                              void* d_out, int out_size, void* d_ws, size_t ws_size,
                              hipStream_t stream) {
  const float* qp    = (const float*)d_in[0];
  const float* cxz   = (const float*)d_in[1];
  const float* cxy   = (const float*)d_in[2];
  const float* cyz   = (const float*)d_in[3];
  const float* w_off = (const float*)d_in[4];
  const float* b_off = (const float*)d_in[5];
  const float* w_q   = (const float*)d_in[6];
  const float* b_q   = (const float*)d_in[7];
  const float* w_k   = (const float*)d_in[8];
  const float* b_k   = (const float*)d_in[9];   (void)b_k; // cancels in softmax
  const float* w_v   = (const float*)d_in[10];
  const float* b_v   = (const float*)d_in[11];
  const float* w_out = (const float*)d_in[12];
  const float* b_out = (const float*)d_in[13];
  float* out = (float*)d_out;
  (void)in_sizes; (void)n_in; (void)out_size; (void)ws_size;

  float* ws      = (float*)d_ws;
  float* planesT = ws + WS_PLANES;
  float* feat    = ws + WS_FEAT;
  float* qk      = ws + WS_QK;
  float* aux     = ws + WS_AUX;
  float* wf      = ws + WS_WF;
  unsigned* perm = (unsigned*)(ws + WS_PERM);

  hipLaunchKernelGGL(sortk, dim3(BS / PAIR_B), dim3(1024), 0, stream, qp, perm);

  for (int pair = 0; pair < BS / PAIR_B; ++pair) {
    int b0 = pair * PAIR_B;
    hipLaunchKernelGGL(tpk2, dim3(3 * PAIR_B * 512), dim3(256), 0, stream,
                       cxz, cxy, cyz, planesT, b0);
    hipLaunchKernelGGL(featk, dim3(PAIR_Q / QTF), dim3(256), 0, stream,
                       qp, planesT, w_off, b_off, w_q, b_q, w_k,
                       feat, aux, qk, b0);
    hipLaunchKernelGGL(attnk, dim3(PAIR_Q / 2), dim3(256), 0, stream,
                       planesT, aux, qk, perm + (size_t)pair * PAIR_Q, wf);
    hipLaunchKernelGGL(epik, dim3(PAIR_Q / QTE), dim3(256), 0, stream,
                       wf, feat, w_v, b_v, w_out, b_out, out, b0);
  }
}